// Round 1
// baseline (451.068 us; speedup 1.0000x reference)
//
#include <hip/hip_runtime.h>
#include <hip/hip_bf16.h>

#define Bn 16
#define Hn 512
#define Wn 512
#define RAD 48

// ---------------------------------------------------------------------------
// K1: boundary = dilate3(mask & ~erode3(mask)), zero padding outside image.
// Block 32x32, LDS-tiled with halo 2 (binarized mask) -> halo 1 (contour).
// ---------------------------------------------------------------------------
__global__ __launch_bounds__(1024) void k_boundary(
    const float* __restrict__ tgt, unsigned char* __restrict__ bnd) {
  __shared__ unsigned char bin[36][36];
  __shared__ unsigned char cont[34][34];
  const int b = blockIdx.z;
  const int x0 = blockIdx.x * 32, y0 = blockIdx.y * 32;
  const int tid = threadIdx.y * 32 + threadIdx.x;
  const float* m = tgt + (size_t)b * Hn * Wn;

  for (int idx = tid; idx < 36 * 36; idx += 1024) {
    int ly = idx / 36, lx = idx % 36;
    int y = y0 + ly - 2, x = x0 + lx - 2;
    unsigned char v = 0;
    if (y >= 0 && y < Hn && x >= 0 && x < Wn)
      v = (m[(size_t)y * Wn + x] > 0.5f) ? 1 : 0;
    bin[ly][lx] = v;
  }
  __syncthreads();

  for (int idx = tid; idx < 34 * 34; idx += 1024) {
    int cy = idx / 34, cx = idx % 34;  // center at bin[cy+1][cx+1]
    unsigned char c = 0;
    if (bin[cy + 1][cx + 1]) {
      // contour iff some 3x3 neighbor (incl. out-of-image zeros) is 0
      int allone = bin[cy][cx] & bin[cy][cx + 1] & bin[cy][cx + 2] &
                   bin[cy + 1][cx] & bin[cy + 1][cx + 2] &
                   bin[cy + 2][cx] & bin[cy + 2][cx + 1] & bin[cy + 2][cx + 2];
      c = allone ? 0 : 1;
    }
    cont[cy][cx] = c;
  }
  __syncthreads();

  const int ty = threadIdx.y, tx = threadIdx.x;
  unsigned char o = cont[ty][tx] | cont[ty][tx + 1] | cont[ty][tx + 2] |
                    cont[ty + 1][tx] | cont[ty + 1][tx + 1] | cont[ty + 1][tx + 2] |
                    cont[ty + 2][tx] | cont[ty + 2][tx + 1] | cont[ty + 2][tx + 2];
  bnd[((size_t)b * Hn + (y0 + ty)) * Wn + (x0 + tx)] = o;
}

// ---------------------------------------------------------------------------
// K2: vertical 1-D distance transform per column (two sweeps), capped at 255.
// Thread per (image, column); adjacent threads -> adjacent columns -> coalesced.
// ---------------------------------------------------------------------------
__global__ __launch_bounds__(256) void k_vdt(
    const unsigned char* __restrict__ bnd, unsigned char* __restrict__ dv) {
  const int t = blockIdx.x * blockDim.x + threadIdx.x;
  if (t >= Bn * Wn) return;
  const int b = t / Wn, j = t % Wn;
  const unsigned char* bp = bnd + (size_t)b * Hn * Wn + j;
  unsigned char* dp = dv + (size_t)b * Hn * Wn + j;

  int d = 255;
#pragma unroll 8
  for (int i = 0; i < Hn; ++i) {
    int bb = bp[(size_t)i * Wn];
    d = bb ? 0 : min(d + 1, 255);
    dp[(size_t)i * Wn] = (unsigned char)d;
  }
  d = 255;
#pragma unroll 8
  for (int i = Hn - 1; i >= 0; --i) {
    int bb = bp[(size_t)i * Wn];
    d = bb ? 0 : min(d + 1, 255);
    int prev = dp[(size_t)i * Wn];
    dp[(size_t)i * Wn] = (unsigned char)min(prev, d);
  }
}

// ---------------------------------------------------------------------------
// K3: horizontal chamfer combine (window +-RAD), weight, BCE, partial sums.
// One block = 256 consecutive pixels of one row.
// ---------------------------------------------------------------------------
__global__ __launch_bounds__(256) void k_loss(
    const float* __restrict__ x, const float* __restrict__ tgt,
    const unsigned char* __restrict__ dv, float* __restrict__ partial) {
  __shared__ unsigned char dvs[256 + 2 * RAD];
  __shared__ float red[4];
  const int b = blockIdx.z, i = blockIdx.y, j0 = blockIdx.x * 256;
  const int tx = threadIdx.x;
  const unsigned char* dvrow = dv + ((size_t)b * Hn + i) * Wn;

  for (int idx = tx; idx < 256 + 2 * RAD; idx += 256) {
    int jj = j0 - RAD + idx;
    dvs[idx] = (jj >= 0 && jj < Wn) ? dvrow[jj] : (unsigned char)255;
  }
  __syncthreads();

  const float A = 0.955f;              // W_EDGE
  const float BA = 1.3693f - 0.955f;   // W_DIAG - W_EDGE
  float d = 1e30f;
#pragma unroll 8
  for (int k = -RAD; k <= RAD; ++k) {
    float u = (float)(k < 0 ? -k : k);
    float v = (float)dvs[tx + RAD + k];
    d = fminf(d, A * fmaxf(u, v) + BA * fminf(u, v));
  }
  float w = expf(-d * (1.0f / 3.0f)) + 0.1f;

  const size_t off = ((size_t)b * Hn + i) * Wn + (j0 + tx);
  float L = x[off];
  L = fminf(fmaxf(L, -16.118095f), 16.118095f);  // logit(clip(sigmoid)) == clamp
  float t = tgt[off];
  float bce = fmaxf(L, 0.0f) - L * t + log1pf(expf(-fabsf(L)));
  float val = bce * w;

  // wave64 reduce, then cross-wave via LDS
#pragma unroll
  for (int s = 32; s; s >>= 1) val += __shfl_down(val, s, 64);
  const int wid = tx >> 6, lane = tx & 63;
  if (lane == 0) red[wid] = val;
  __syncthreads();
  if (tx == 0) {
    float s = red[0] + red[1] + red[2] + red[3];
    int pid = (b * Hn + i) * (Wn / 256) + blockIdx.x;
    partial[pid] = s;
  }
}

// ---------------------------------------------------------------------------
// K4: deterministic final reduction (double accumulation) -> mean.
// ---------------------------------------------------------------------------
__global__ __launch_bounds__(256) void k_final(
    const float* __restrict__ partial, int n, float* __restrict__ out) {
  __shared__ double red[256];
  double s = 0.0;
  for (int idx = threadIdx.x; idx < n; idx += 256) s += (double)partial[idx];
  red[threadIdx.x] = s;
  __syncthreads();
  for (int st = 128; st; st >>= 1) {
    if (threadIdx.x < st) red[threadIdx.x] += red[threadIdx.x + st];
    __syncthreads();
  }
  if (threadIdx.x == 0)
    out[0] = (float)(red[0] / (double)((size_t)Bn * Hn * Wn));
}

extern "C" void kernel_launch(void* const* d_in, const int* in_sizes, int n_in,
                              void* d_out, int out_size, void* d_ws, size_t ws_size,
                              hipStream_t stream) {
  const float* inputs = (const float*)d_in[0];   // [B,1,H,W] f32
  const float* targets = (const float*)d_in[1];  // [B,1,H,W] f32
  float* out = (float*)d_out;

  const size_t npix = (size_t)Bn * Hn * Wn;
  unsigned char* bnd = (unsigned char*)d_ws;                 // 4 MB
  unsigned char* dv = (unsigned char*)d_ws + npix;           // 4 MB
  float* partial = (float*)((unsigned char*)d_ws + 2 * npix);  // 64 KB
  const int nPartial = Bn * Hn * (Wn / 256);  // 16384

  {
    dim3 blk(32, 32, 1), grd(Wn / 32, Hn / 32, Bn);
    hipLaunchKernelGGL(k_boundary, grd, blk, 0, stream, targets, bnd);
  }
  {
    int nthr = Bn * Wn;
    hipLaunchKernelGGL(k_vdt, dim3((nthr + 255) / 256), dim3(256), 0, stream,
                       bnd, dv);
  }
  {
    dim3 blk(256, 1, 1), grd(Wn / 256, Hn, Bn);
    hipLaunchKernelGGL(k_loss, grd, blk, 0, stream, inputs, targets, dv, partial);
  }
  hipLaunchKernelGGL(k_final, dim3(1), dim3(256), 0, stream, partial, nPartial,
                     out);
}

// Round 3
// 97.370 us; speedup vs baseline: 4.6325x; 4.6325x over previous
//
#include <hip/hip_runtime.h>

#define Bn 16
#define Hn 512
#define Wn 512
#define RAD 32
#define NSEG 8
#define SEGH 64
#define WPR 16  // 32-bit words per row (Wn/32)

typedef _Float16 h2 __attribute__((ext_vector_type(2)));

// ---------------------------------------------------------------------------
// K1: boundary = dilate3(mask & ~erode3(mask)), bit-packed output (1 bit/px).
// ---------------------------------------------------------------------------
__global__ __launch_bounds__(1024) void k_boundary(
    const float* __restrict__ tgt, unsigned int* __restrict__ bbits) {
  __shared__ unsigned char bin[36][36];
  __shared__ unsigned char cont[34][34];
  const int b = blockIdx.z;
  const int x0 = blockIdx.x * 32, y0 = blockIdx.y * 32;
  const int tid = threadIdx.y * 32 + threadIdx.x;
  const float* m = tgt + (size_t)b * Hn * Wn;

  for (int idx = tid; idx < 36 * 36; idx += 1024) {
    int ly = idx / 36, lx = idx % 36;
    int y = y0 + ly - 2, x = x0 + lx - 2;
    unsigned char v = 0;
    if (y >= 0 && y < Hn && x >= 0 && x < Wn)
      v = (m[(size_t)y * Wn + x] > 0.5f) ? 1 : 0;
    bin[ly][lx] = v;
  }
  __syncthreads();

  for (int idx = tid; idx < 34 * 34; idx += 1024) {
    int cy = idx / 34, cx = idx % 34;
    unsigned char c = 0;
    if (bin[cy + 1][cx + 1]) {
      int a = bin[cy][cx] & bin[cy][cx + 1] & bin[cy][cx + 2] &
              bin[cy + 1][cx] & bin[cy + 1][cx + 2] &
              bin[cy + 2][cx] & bin[cy + 2][cx + 1] & bin[cy + 2][cx + 2];
      c = a ? 0 : 1;
    }
    cont[cy][cx] = c;
  }
  __syncthreads();

  const int ty = threadIdx.y, tx = threadIdx.x;
  unsigned char o = cont[ty][tx] | cont[ty][tx + 1] | cont[ty][tx + 2] |
                    cont[ty + 1][tx] | cont[ty + 1][tx + 1] | cont[ty + 1][tx + 2] |
                    cont[ty + 2][tx] | cont[ty + 2][tx + 1] | cont[ty + 2][tx + 2];
  unsigned long long mask = __ballot(o != 0);
  const int lane = tid & 63;
  if (lane == 0) {
    int wv = tid >> 6;  // wave 0..15 covers rows 2*wv, 2*wv+1
    int y = y0 + 2 * wv;
    size_t w0 = ((size_t)b * Hn + y) * WPR + blockIdx.x;
    bbits[w0] = (unsigned int)(mask & 0xffffffffull);
    bbits[w0 + WPR] = (unsigned int)(mask >> 32);
  }
}

// ---------------------------------------------------------------------------
// K2: per-segment vertical DT (64 rows) + first/last boundary row summaries.
// ---------------------------------------------------------------------------
__global__ __launch_bounds__(256) void k_vdt_seg(
    const unsigned int* __restrict__ bbits, unsigned char* __restrict__ dseg,
    short* __restrict__ Bfirst, short* __restrict__ Blast) {
  const int t = blockIdx.x * 256 + threadIdx.x;  // Bn*NSEG*Wn = 65536
  const int col = t & (Wn - 1);
  const int rest = t >> 9;
  const int seg = rest & (NSEG - 1);
  const int b = rest >> 3;
  const int i0 = seg * SEGH;
  const unsigned int* wp = bbits + ((size_t)b * Hn + i0) * WPR + (col >> 5);
  unsigned char* dp = dseg + ((size_t)b * Hn + i0) * Wn + col;
  const int sh = col & 31;

  int d = 255, first = 30000, last = -30000;
#pragma unroll 4
  for (int r = 0; r < SEGH; ++r) {
    int bb = (wp[(size_t)r * WPR] >> sh) & 1;
    int i = i0 + r;
    d = bb ? 0 : min(d + 1, 255);
    first = min(first, bb ? i : 30000);
    last = max(last, bb ? i : -30000);
    dp[(size_t)r * Wn] = (unsigned char)d;
  }
  d = 255;
#pragma unroll 4
  for (int r = SEGH - 1; r >= 0; --r) {
    int bb = (wp[(size_t)r * WPR] >> sh) & 1;
    d = bb ? 0 : min(d + 1, 255);
    int prev = dp[(size_t)r * Wn];
    dp[(size_t)r * Wn] = (unsigned char)min(prev, d);
  }
  const int sidx = ((b * NSEG + seg) << 9) + col;
  Bfirst[sidx] = (short)first;
  Blast[sidx] = (short)last;
}

// ---------------------------------------------------------------------------
// K3: cross-segment prefix/suffix: nearest boundary row below/above each seg.
// ---------------------------------------------------------------------------
__global__ __launch_bounds__(256) void k_comb(
    const short* __restrict__ Bfirst, const short* __restrict__ Blast,
    short* __restrict__ before, short* __restrict__ after) {
  const int t = blockIdx.x * 256 + threadIdx.x;  // Bn*Wn = 8192
  if (t >= Bn * Wn) return;
  const int col = t & (Wn - 1);
  const int b = t >> 9;
  const int base = (b * NSEG) << 9;
  int run = -30000;
#pragma unroll
  for (int s = 0; s < NSEG; ++s) {
    int idx = base + (s << 9) + col;
    before[idx] = (short)run;
    run = max(run, (int)Blast[idx]);
  }
  run = 30000;
#pragma unroll
  for (int s = NSEG - 1; s >= 0; --s) {
    int idx = base + (s << 9) + col;
    after[idx] = (short)run;
    run = min(run, (int)Bfirst[idx]);
  }
}

// ---------------------------------------------------------------------------
// K4: horizontal chamfer combine (packed f16, 2 px/thread: tx and tx+256),
//     weight, BCE, per-row partial sum. Block = one image row.
// ---------------------------------------------------------------------------
__global__ __launch_bounds__(256) void k_loss(
    const float* __restrict__ x, const float* __restrict__ tgt,
    const unsigned char* __restrict__ dseg, const short* __restrict__ before,
    const short* __restrict__ after, float* __restrict__ partial) {
  __shared__ h2 dvs[320];  // entry e: (dv[e-32], dv[e+224])
  __shared__ float red[4];
  const int b = blockIdx.z, i = blockIdx.y;
  const int tx = threadIdx.x;
  const int seg = i >> 6;
  const size_t rowoff = ((size_t)b * Hn + i) * Wn;
  const int sbase = (b * NSEG + seg) << 9;

  for (int e = tx; e < 320; e += 256) {
    float f0, f1;
    {
      int c = e - RAD;
      int dv = 255;
      if (c >= 0 && c < Wn) {
        int ds = dseg[rowoff + c];
        int bf = before[sbase + c];
        int af = after[sbase + c];
        dv = min(min(ds, i - bf), min(af - i, 255));
      }
      f0 = (float)dv;
    }
    {
      int c = e - RAD + 256;
      int dv = 255;
      if (c < Wn) {
        int ds = dseg[rowoff + c];
        int bf = before[sbase + c];
        int af = after[sbase + c];
        dv = min(min(ds, i - bf), min(af - i, 255));
      }
      f1 = (float)dv;
    }
    h2 pk;
    pk.x = (_Float16)f0;
    pk.y = (_Float16)f1;
    dvs[e] = pk;
  }
  __syncthreads();

  const h2 A2 = {(_Float16)0.955f, (_Float16)0.955f};
  const h2 BA2 = {(_Float16)0.4143f, (_Float16)0.4143f};  // W_DIAG - W_EDGE
  h2 acc0 = {(_Float16)300.0f, (_Float16)300.0f};
  h2 acc1 = acc0, acc2 = acc0, acc3 = acc0;
#pragma unroll
  for (int k = -RAD; k <= RAD; ++k) {
    h2 v2 = dvs[tx + RAD + k];
    float uf = (float)(k < 0 ? -k : k);
    h2 u2 = {(_Float16)uf, (_Float16)uf};
    h2 mx = __builtin_elementwise_max(u2, v2);
    h2 mn = __builtin_elementwise_min(u2, v2);
    h2 c = mx * A2 + mn * BA2;
    const int sel = k & 3;
    if (sel == 0) acc0 = __builtin_elementwise_min(acc0, c);
    else if (sel == 1) acc1 = __builtin_elementwise_min(acc1, c);
    else if (sel == 2) acc2 = __builtin_elementwise_min(acc2, c);
    else acc3 = __builtin_elementwise_min(acc3, c);
  }
  h2 am = __builtin_elementwise_min(__builtin_elementwise_min(acc0, acc1),
                                    __builtin_elementwise_min(acc2, acc3));
  float d0 = (float)am.x, d1 = (float)am.y;

  float w0 = __expf(-d0 * (1.0f / 3.0f)) + 0.1f;
  float w1 = __expf(-d1 * (1.0f / 3.0f)) + 0.1f;

  float L0 = x[rowoff + tx], L1 = x[rowoff + tx + 256];
  float t0 = tgt[rowoff + tx], t1 = tgt[rowoff + tx + 256];
  L0 = fminf(fmaxf(L0, -16.118095f), 16.118095f);
  L1 = fminf(fmaxf(L1, -16.118095f), 16.118095f);
  float bce0 = fmaxf(L0, 0.0f) - L0 * t0 + log1pf(__expf(-fabsf(L0)));
  float bce1 = fmaxf(L1, 0.0f) - L1 * t1 + log1pf(__expf(-fabsf(L1)));
  float val = bce0 * w0 + bce1 * w1;

#pragma unroll
  for (int s = 32; s; s >>= 1) val += __shfl_down(val, s, 64);
  if ((tx & 63) == 0) red[tx >> 6] = val;
  __syncthreads();
  if (tx == 0) partial[b * Hn + i] = red[0] + red[1] + red[2] + red[3];
}

// ---------------------------------------------------------------------------
// K5: deterministic final reduction (double accumulation) -> mean.
// ---------------------------------------------------------------------------
__global__ __launch_bounds__(1024) void k_final(
    const float* __restrict__ partial, float* __restrict__ out) {
  __shared__ double red[1024];
  double s = 0.0;
  for (int idx = threadIdx.x; idx < Bn * Hn; idx += 1024) s += (double)partial[idx];
  red[threadIdx.x] = s;
  __syncthreads();
  for (int st = 512; st; st >>= 1) {
    if (threadIdx.x < st) red[threadIdx.x] += red[threadIdx.x + st];
    __syncthreads();
  }
  if (threadIdx.x == 0)
    out[0] = (float)(red[0] / (double)((size_t)Bn * Hn * Wn));
}

extern "C" void kernel_launch(void* const* d_in, const int* in_sizes, int n_in,
                              void* d_out, int out_size, void* d_ws, size_t ws_size,
                              hipStream_t stream) {
  const float* inputs = (const float*)d_in[0];
  const float* targets = (const float*)d_in[1];
  float* out = (float*)d_out;

  unsigned char* ws = (unsigned char*)d_ws;
  const size_t npix = (size_t)Bn * Hn * Wn;
  const size_t nsum = (size_t)Bn * NSEG * Wn;  // 65536 summary entries
  unsigned int* bbits = (unsigned int*)ws;                       // 512 KB
  unsigned char* dseg = ws + (npix / 8);                         // 4 MB
  short* Bfirst = (short*)(ws + npix / 8 + npix);                // 128 KB
  short* Blast = Bfirst + nsum;                                  // 128 KB
  short* before = Blast + nsum;                                  // 128 KB
  short* after = before + nsum;                                  // 128 KB
  float* partial = (float*)(after + nsum);                       // 32 KB

  {
    dim3 blk(32, 32, 1), grd(Wn / 32, Hn / 32, Bn);
    hipLaunchKernelGGL(k_boundary, grd, blk, 0, stream, targets, bbits);
  }
  {
    int nthr = Bn * NSEG * Wn;
    hipLaunchKernelGGL(k_vdt_seg, dim3(nthr / 256), dim3(256), 0, stream,
                       bbits, dseg, Bfirst, Blast);
  }
  {
    int nthr = Bn * Wn;
    hipLaunchKernelGGL(k_comb, dim3((nthr + 255) / 256), dim3(256), 0, stream,
                       Bfirst, Blast, before, after);
  }
  {
    dim3 blk(256, 1, 1), grd(1, Hn, Bn);
    hipLaunchKernelGGL(k_loss, grd, blk, 0, stream, inputs, targets, dseg,
                       before, after, partial);
  }
  hipLaunchKernelGGL(k_final, dim3(1), dim3(1024), 0, stream, partial, out);
}

// Round 4
// 41.720 us; speedup vs baseline: 10.8119x; 2.3339x over previous
//
#include <hip/hip_runtime.h>

#define Bn 16
#define Hn 512
#define Wn 512
#define RAD 24
#define NSEG 16
#define SEGH 32
#define WPR 16  // 32-bit words per row (Wn/32)

typedef _Float16 h2 __attribute__((ext_vector_type(2)));

// ---------------------------------------------------------------------------
// K0: binarize targets and pack to 1 bit/px (coalesced float4 reads).
// Block: 256 threads -> 256 output words (8192 floats).
// ---------------------------------------------------------------------------
__global__ __launch_bounds__(256) void k_pack(
    const float* __restrict__ tgt, unsigned int* __restrict__ mbits) {
  __shared__ int nib[2048];
  const int tid = threadIdx.x;
  const size_t base4 = (size_t)blockIdx.x * 2048;
  const float4* t4 = (const float4*)tgt;
#pragma unroll
  for (int j = 0; j < 8; ++j) {
    float4 v = t4[base4 + tid + 256 * j];
    int n = (v.x > 0.5f ? 1 : 0) | (v.y > 0.5f ? 2 : 0) |
            (v.z > 0.5f ? 4 : 0) | (v.w > 0.5f ? 8 : 0);
    nib[tid + 256 * j] = n;
  }
  __syncthreads();
  unsigned int w = 0;
#pragma unroll
  for (int c = 0; c < 8; ++c)
    w |= ((unsigned int)nib[8 * tid + c]) << (4 * c);
  mbits[(size_t)blockIdx.x * 256 + tid] = w;
}

// ---------------------------------------------------------------------------
// K1: bitwise morphology: boundary = dilate3(m & ~erode3(m)), zero outside.
// One thread per 32-bit word.
// ---------------------------------------------------------------------------
__device__ __forceinline__ unsigned int ldw(const unsigned int* p, int b,
                                            int y, int w) {
  if (y < 0 || y >= Hn || w < 0 || w >= WPR) return 0u;
  return p[((size_t)b * Hn + y) * WPR + w];
}

__global__ __launch_bounds__(256) void k_morph(
    const unsigned int* __restrict__ mbits, unsigned int* __restrict__ bbits) {
  const int t = blockIdx.x * 256 + threadIdx.x;  // Bn*Hn*WPR = 131072
  const int w = t & 15, y = (t >> 4) & (Hn - 1), b = t >> 13;
  unsigned int m[5][5];
#pragma unroll
  for (int dy = 0; dy < 5; ++dy)
#pragma unroll
    for (int dx = 0; dx < 5; ++dx)
      m[dy][dx] = ldw(mbits, b, y + dy - 2, w + dx - 2);
  // horizontal 3-erosion bands for rows y-2..y+2, words w-1..w+1
  unsigned int hb[5][3];
#pragma unroll
  for (int dy = 0; dy < 5; ++dy)
#pragma unroll
    for (int dx = 0; dx < 3; ++dx) {
      unsigned int l = m[dy][dx], c = m[dy][dx + 1], r = m[dy][dx + 2];
      hb[dy][dx] = c & ((c << 1) | (l >> 31)) & ((c >> 1) | (r << 31));
    }
  unsigned int D = 0;
#pragma unroll
  for (int dy = 1; dy <= 3; ++dy) {  // contour rows y-1..y+1
    unsigned int C[3];
#pragma unroll
    for (int dx = 0; dx < 3; ++dx) {
      unsigned int E = hb[dy - 1][dx] & hb[dy][dx] & hb[dy + 1][dx];
      C[dx] = m[dy][dx + 1] & ~E;
    }
    D |= C[1] | ((C[1] << 1) | (C[0] >> 31)) | ((C[1] >> 1) | (C[2] << 31));
  }
  bbits[t] = D;
}

// ---------------------------------------------------------------------------
// K2: per-segment vertical DT (32 rows, all in registers) + first/last rows.
// ---------------------------------------------------------------------------
__global__ __launch_bounds__(256) void k_vdt_seg(
    const unsigned int* __restrict__ bbits, unsigned char* __restrict__ dseg,
    short* __restrict__ Bf, short* __restrict__ Bl) {
  const int t = blockIdx.x * 256 + threadIdx.x;  // Bn*NSEG*Wn = 131072
  const int col = t & (Wn - 1);
  const int rest = t >> 9;
  const int seg = rest & (NSEG - 1);
  const int b = rest >> 4;
  const int i0 = seg * SEGH;
  const unsigned int* wp = bbits + ((size_t)b * Hn + i0) * WPR + (col >> 5);
  const int sh = col & 31;

  unsigned int bits = 0;  // bit r = boundary at row i0+r
#pragma unroll
  for (int r = 0; r < SEGH; ++r)
    bits |= ((wp[(size_t)r * WPR] >> sh) & 1u) << r;

  int first = 30000, last = -30000;
  if (bits) {
    first = i0 + __ffs(bits) - 1;
    last = i0 + 31 - __clz((int)bits);
  }

  unsigned char dc[SEGH];
  int d = 255;
#pragma unroll
  for (int r = 0; r < SEGH; ++r) {
    d = ((bits >> r) & 1u) ? 0 : min(d + 1, 255);
    dc[r] = (unsigned char)d;
  }
  unsigned char* dp = dseg + ((size_t)b * Hn + i0) * Wn + col;
  d = 255;
#pragma unroll
  for (int r = SEGH - 1; r >= 0; --r) {
    d = ((bits >> r) & 1u) ? 0 : min(d + 1, 255);
    dp[(size_t)r * Wn] = (unsigned char)min((int)dc[r], d);
  }
  const int sidx = ((b * NSEG + seg) << 9) + col;
  Bf[sidx] = (short)first;
  Bl[sidx] = (short)last;
}

// ---------------------------------------------------------------------------
// K3: cross-segment prefix/suffix of boundary rows.
// ---------------------------------------------------------------------------
__global__ __launch_bounds__(256) void k_comb(
    const short* __restrict__ Bf, const short* __restrict__ Bl,
    short* __restrict__ before, short* __restrict__ after) {
  const int t = blockIdx.x * 256 + threadIdx.x;  // Bn*Wn = 8192
  const int col = t & (Wn - 1);
  const int b = t >> 9;
  const int base = (b * NSEG) << 9;
  int run = -30000;
#pragma unroll
  for (int s = 0; s < NSEG; ++s) {
    int idx = base + (s << 9) + col;
    before[idx] = (short)run;
    run = max(run, (int)Bl[idx]);
  }
  run = 30000;
#pragma unroll
  for (int s = NSEG - 1; s >= 0; --s) {
    int idx = base + (s << 9) + col;
    after[idx] = (short)run;
    run = min(run, (int)Bf[idx]);
  }
}

// ---------------------------------------------------------------------------
// K4: chamfer window (paired ±k, 2 rows/block, packed f16), weight, BCE, sum.
// ---------------------------------------------------------------------------
__global__ __launch_bounds__(256) void k_loss(
    const float* __restrict__ x, const unsigned int* __restrict__ mbits,
    const unsigned char* __restrict__ dseg, const short* __restrict__ before,
    const short* __restrict__ after, float* __restrict__ partial) {
  __shared__ h2 dvs[2][304];  // [row][e]: (dv[e-RAD], dv[e-RAD+256])
  __shared__ float red[4];
  const int b = blockIdx.z, by = blockIdx.y;
  const int i0 = 2 * by;
  const int tx = threadIdx.x;
  const int seg = i0 >> 5;  // SEGH=32; rows i0,i0+1 share a segment
  const size_t row0 = ((size_t)b * Hn + i0) * Wn;
  const int sbase = (b * NSEG + seg) << 9;

  for (int e = tx; e < 304; e += 256) {
    int c0 = e - RAD;        // in [-24, 279]
    int c1 = c0 + 256;       // in [232, 535]
    int in0 = (c0 >= 0);
    int in1 = (c1 < Wn);
    int bf0 = 0, af0 = 0, bf1 = 0, af1 = 0;
    if (in0) { bf0 = before[sbase + c0]; af0 = after[sbase + c0]; }
    if (in1) { bf1 = before[sbase + c1]; af1 = after[sbase + c1]; }
#pragma unroll
    for (int rr = 0; rr < 2; ++rr) {
      int i = i0 + rr;
      int dv0 = 255, dv1 = 255;
      if (in0) {
        int ds = dseg[row0 + (size_t)rr * Wn + c0];
        dv0 = min(min(ds, i - bf0), min(af0 - i, 255));
      }
      if (in1) {
        int ds = dseg[row0 + (size_t)rr * Wn + c1];
        dv1 = min(min(ds, i - bf1), min(af1 - i, 255));
      }
      h2 pk;
      pk.x = (_Float16)(float)dv0;
      pk.y = (_Float16)(float)dv1;
      dvs[rr][e] = pk;
    }
  }
  __syncthreads();

  const h2 A2 = {(_Float16)0.955f, (_Float16)0.955f};
  const h2 BA2 = {(_Float16)0.4143f, (_Float16)0.4143f};
  h2 a00 = {(_Float16)300.0f, (_Float16)300.0f};
  h2 a01 = a00, a10 = a00, a11 = a00;
#pragma unroll
  for (int k = 0; k <= RAD; ++k) {
    const h2 c1 = {(_Float16)(0.955f * k), (_Float16)(0.955f * k)};
    const h2 c2 = {(_Float16)(0.4143f * k), (_Float16)(0.4143f * k)};
    {
      h2 v = __builtin_elementwise_min(dvs[0][tx + RAD - k], dvs[0][tx + RAD + k]);
      h2 f = __builtin_elementwise_max(v * BA2 + c1, v * A2 + c2);
      if (k & 1) a01 = __builtin_elementwise_min(a01, f);
      else       a00 = __builtin_elementwise_min(a00, f);
    }
    {
      h2 v = __builtin_elementwise_min(dvs[1][tx + RAD - k], dvs[1][tx + RAD + k]);
      h2 f = __builtin_elementwise_max(v * BA2 + c1, v * A2 + c2);
      if (k & 1) a11 = __builtin_elementwise_min(a11, f);
      else       a10 = __builtin_elementwise_min(a10, f);
    }
  }
  h2 am0 = __builtin_elementwise_min(a00, a01);
  h2 am1 = __builtin_elementwise_min(a10, a11);
  float d00 = (float)am0.x, d01 = (float)am0.y;
  float d10 = (float)am1.x, d11 = (float)am1.y;

  float w00 = __expf(d00 * (-1.0f / 3.0f)) + 0.1f;
  float w01 = __expf(d01 * (-1.0f / 3.0f)) + 0.1f;
  float w10 = __expf(d10 * (-1.0f / 3.0f)) + 0.1f;
  float w11 = __expf(d11 * (-1.0f / 3.0f)) + 0.1f;

  // targets as bits
  const int wi = tx >> 5, sh = tx & 31;
  unsigned int mw00 = mbits[((size_t)b * Hn + i0) * WPR + wi];
  unsigned int mw01 = mbits[((size_t)b * Hn + i0) * WPR + 8 + wi];
  unsigned int mw10 = mbits[((size_t)b * Hn + i0 + 1) * WPR + wi];
  unsigned int mw11 = mbits[((size_t)b * Hn + i0 + 1) * WPR + 8 + wi];
  float t00 = (float)((mw00 >> sh) & 1u);
  float t01 = (float)((mw01 >> sh) & 1u);
  float t10 = (float)((mw10 >> sh) & 1u);
  float t11 = (float)((mw11 >> sh) & 1u);

  float L00 = x[row0 + tx], L01 = x[row0 + tx + 256];
  float L10 = x[row0 + Wn + tx], L11 = x[row0 + Wn + tx + 256];
  L00 = fminf(fmaxf(L00, -16.118095f), 16.118095f);
  L01 = fminf(fmaxf(L01, -16.118095f), 16.118095f);
  L10 = fminf(fmaxf(L10, -16.118095f), 16.118095f);
  L11 = fminf(fmaxf(L11, -16.118095f), 16.118095f);
  float bce00 = fmaxf(L00, 0.0f) - L00 * t00 + __logf(1.0f + __expf(-fabsf(L00)));
  float bce01 = fmaxf(L01, 0.0f) - L01 * t01 + __logf(1.0f + __expf(-fabsf(L01)));
  float bce10 = fmaxf(L10, 0.0f) - L10 * t10 + __logf(1.0f + __expf(-fabsf(L10)));
  float bce11 = fmaxf(L11, 0.0f) - L11 * t11 + __logf(1.0f + __expf(-fabsf(L11)));
  float val = bce00 * w00 + bce01 * w01 + bce10 * w10 + bce11 * w11;

#pragma unroll
  for (int s = 32; s; s >>= 1) val += __shfl_down(val, s, 64);
  if ((tx & 63) == 0) red[tx >> 6] = val;
  __syncthreads();
  if (tx == 0) partial[(b << 8) + by] = red[0] + red[1] + red[2] + red[3];
}

// ---------------------------------------------------------------------------
// K5: deterministic final reduction (double accumulation) -> mean.
// ---------------------------------------------------------------------------
__global__ __launch_bounds__(1024) void k_final(
    const float* __restrict__ partial, float* __restrict__ out) {
  __shared__ double red[1024];
  double s = 0.0;
  for (int idx = threadIdx.x; idx < Bn * 256; idx += 1024)
    s += (double)partial[idx];
  red[threadIdx.x] = s;
  __syncthreads();
  for (int st = 512; st; st >>= 1) {
    if (threadIdx.x < st) red[threadIdx.x] += red[threadIdx.x + st];
    __syncthreads();
  }
  if (threadIdx.x == 0)
    out[0] = (float)(red[0] / (double)((size_t)Bn * Hn * Wn));
}

extern "C" void kernel_launch(void* const* d_in, const int* in_sizes, int n_in,
                              void* d_out, int out_size, void* d_ws, size_t ws_size,
                              hipStream_t stream) {
  const float* inputs = (const float*)d_in[0];
  const float* targets = (const float*)d_in[1];
  float* out = (float*)d_out;

  unsigned char* ws = (unsigned char*)d_ws;
  const int nwords = Bn * Hn * WPR;  // 131072
  unsigned int* mbits = (unsigned int*)ws;                       // 512 KB
  unsigned int* bbits = (unsigned int*)(ws + (512 << 10));       // 512 KB
  unsigned char* dseg = ws + (1 << 20);                          // 4 MB
  short* Bf = (short*)(ws + 5u * (1 << 20));                     // 256 KB
  short* Bl = Bf + nwords;                                       // 256 KB
  short* before = Bl + nwords;                                   // 256 KB
  short* after = before + nwords;                                // 256 KB
  float* partial = (float*)(after + nwords);                     // 16 KB

  hipLaunchKernelGGL(k_pack, dim3(512), dim3(256), 0, stream, targets, mbits);
  hipLaunchKernelGGL(k_morph, dim3(512), dim3(256), 0, stream, mbits, bbits);
  hipLaunchKernelGGL(k_vdt_seg, dim3(512), dim3(256), 0, stream, bbits, dseg,
                     Bf, Bl);
  hipLaunchKernelGGL(k_comb, dim3(32), dim3(256), 0, stream, Bf, Bl, before,
                     after);
  {
    dim3 blk(256, 1, 1), grd(1, Hn / 2, Bn);
    hipLaunchKernelGGL(k_loss, grd, blk, 0, stream, inputs, mbits, dseg,
                       before, after, partial);
  }
  hipLaunchKernelGGL(k_final, dim3(1), dim3(1024), 0, stream, partial, out);
}

// Round 5
// 40.408 us; speedup vs baseline: 11.1628x; 1.0325x over previous
//
#include <hip/hip_runtime.h>

#define Bn 16
#define Hn 512
#define Wn 512
#define RAD 24
#define NSEG 16
#define SEGH 32
#define WPR 16  // 32-bit words per row (Wn/32)

typedef _Float16 h2 __attribute__((ext_vector_type(2)));

// ---------------------------------------------------------------------------
// K0: binarize targets and pack to 1 bit/px. 2048 blocks for full occupancy.
// ---------------------------------------------------------------------------
__global__ __launch_bounds__(256) void k_pack(
    const float* __restrict__ tgt, unsigned int* __restrict__ mbits) {
  __shared__ int nib[512];
  const int tid = threadIdx.x;
  const size_t base4 = (size_t)blockIdx.x * 512;
  const float4* t4 = (const float4*)tgt;
#pragma unroll
  for (int j = 0; j < 2; ++j) {
    float4 v = t4[base4 + tid + 256 * j];
    int n = (v.x > 0.5f ? 1 : 0) | (v.y > 0.5f ? 2 : 0) |
            (v.z > 0.5f ? 4 : 0) | (v.w > 0.5f ? 8 : 0);
    nib[tid + 256 * j] = n;
  }
  __syncthreads();
  if (tid < 64) {
    unsigned int w = 0;
#pragma unroll
    for (int c = 0; c < 8; ++c)
      w |= ((unsigned int)nib[8 * tid + c]) << (4 * c);
    mbits[(size_t)blockIdx.x * 64 + tid] = w;
  }
}

// ---------------------------------------------------------------------------
// K1: fused morphology + per-segment vertical DT.
// Block: one (image, 32-row segment, 256-col half). LDS-staged mbits tile ->
// word-morph (boundary bits) in LDS -> register vertical DT + first/last.
// ---------------------------------------------------------------------------
__global__ __launch_bounds__(256) void k_vdt(
    const unsigned int* __restrict__ mbits, unsigned char* __restrict__ dseg,
    short* __restrict__ Bf, short* __restrict__ Bl) {
  __shared__ unsigned int lm[36][12];  // rows i0-2..i0+33, words w0-2..w0+9
  __shared__ unsigned int bb[32][8];   // boundary bits, words w0..w0+7
  const int cx = blockIdx.x & 1;
  const int seg = (blockIdx.x >> 1) & (NSEG - 1);
  const int b = blockIdx.x >> 5;
  const int i0 = seg * SEGH;
  const int w0 = cx * 8;
  const int t = threadIdx.x;

  for (int idx = t; idx < 36 * 12; idx += 256) {
    int r = idx / 12, wi = idx % 12;
    int y = i0 - 2 + r, gw = w0 - 2 + wi;
    unsigned int v = 0;
    if (y >= 0 && y < Hn && gw >= 0 && gw < WPR)
      v = mbits[((size_t)b * Hn + y) * WPR + gw];
    lm[r][wi] = v;
  }
  __syncthreads();

  {  // word-morph: thread t -> row i0+rr, word w0+k
    const int rr = t >> 3, k = t & 7;
    unsigned int m[5][5];
#pragma unroll
    for (int dy = 0; dy < 5; ++dy)
#pragma unroll
      for (int dx = 0; dx < 5; ++dx)
        m[dy][dx] = lm[rr + dy][k + dx];
    unsigned int hb[5][3];
#pragma unroll
    for (int dy = 0; dy < 5; ++dy)
#pragma unroll
      for (int dx = 0; dx < 3; ++dx) {
        unsigned int l = m[dy][dx], c = m[dy][dx + 1], r2 = m[dy][dx + 2];
        hb[dy][dx] = c & ((c << 1) | (l >> 31)) & ((c >> 1) | (r2 << 31));
      }
    unsigned int D = 0;
#pragma unroll
    for (int dy = 1; dy <= 3; ++dy) {
      unsigned int C[3];
#pragma unroll
      for (int dx = 0; dx < 3; ++dx) {
        unsigned int E = hb[dy - 1][dx] & hb[dy][dx] & hb[dy + 1][dx];
        C[dx] = m[dy][dx + 1] & ~E;
      }
      D |= C[1] | ((C[1] << 1) | (C[0] >> 31)) | ((C[1] >> 1) | (C[2] << 31));
    }
    bb[rr][k] = D;
  }
  __syncthreads();

  // vertical DT over the 32-row segment, all in registers
  const int col = cx * 256 + t;
  const int sh = t & 31, wq = t >> 5;
  unsigned int bits = 0;
#pragma unroll
  for (int r = 0; r < SEGH; ++r)
    bits |= ((bb[r][wq] >> sh) & 1u) << r;

  int first = 30000, last = -30000;
  if (bits) {
    first = i0 + __ffs(bits) - 1;
    last = i0 + 31 - __clz((int)bits);
  }

  unsigned char dc[SEGH];
  int d = 255;
#pragma unroll
  for (int r = 0; r < SEGH; ++r) {
    d = ((bits >> r) & 1u) ? 0 : min(d + 1, 255);
    dc[r] = (unsigned char)d;
  }
  unsigned char* dp = dseg + ((size_t)b * Hn + i0) * Wn + col;
  d = 255;
#pragma unroll
  for (int r = SEGH - 1; r >= 0; --r) {
    d = ((bits >> r) & 1u) ? 0 : min(d + 1, 255);
    dp[(size_t)r * Wn] = (unsigned char)min((int)dc[r], d);
  }
  const int sidx = ((b * NSEG + seg) << 9) + col;
  Bf[sidx] = (short)first;
  Bl[sidx] = (short)last;
}

// ---------------------------------------------------------------------------
// K2: cross-segment prefix/suffix of boundary rows.
// ---------------------------------------------------------------------------
__global__ __launch_bounds__(256) void k_comb(
    const short* __restrict__ Bf, const short* __restrict__ Bl,
    short* __restrict__ before, short* __restrict__ after) {
  const int t = blockIdx.x * 256 + threadIdx.x;  // Bn*Wn = 8192
  const int col = t & (Wn - 1);
  const int b = t >> 9;
  const int base = (b * NSEG) << 9;
  int run = -30000;
#pragma unroll
  for (int s = 0; s < NSEG; ++s) {
    int idx = base + (s << 9) + col;
    before[idx] = (short)run;
    run = max(run, (int)Bl[idx]);
  }
  run = 30000;
#pragma unroll
  for (int s = NSEG - 1; s >= 0; --s) {
    int idx = base + (s << 9) + col;
    after[idx] = (short)run;
    run = min(run, (int)Bf[idx]);
  }
}

// ---------------------------------------------------------------------------
// K3: chamfer window with wave-uniform early exit. Thread = 1 col x 2 rows
// (packed h2). Block = 256 cols x 2 rows. Exact math: exit only when
// 0.955*k_next >= wave-max of current best.
// ---------------------------------------------------------------------------
__global__ __launch_bounds__(256) void k_loss(
    const float* __restrict__ x, const unsigned int* __restrict__ mbits,
    const unsigned char* __restrict__ dseg, const short* __restrict__ before,
    const short* __restrict__ after, float* __restrict__ partial) {
  __shared__ h2 dvs[304];  // entry e: rows (i0, i0+1) at col c0+e-RAD
  __shared__ float red[4];
  const int cx = blockIdx.x, by = blockIdx.y, b = blockIdx.z;
  const int i0 = 2 * by;
  const int c0 = cx * 256;
  const int tx = threadIdx.x;
  const int seg = i0 >> 5;
  const size_t row0 = ((size_t)b * Hn + i0) * Wn;
  const int sbase = (b * NSEG + seg) << 9;

  for (int e = tx; e < 304; e += 256) {
    int c = c0 + e - RAD;
    int dv0 = 255, dv1 = 255;
    if (c >= 0 && c < Wn) {
      int bf = before[sbase + c], af = after[sbase + c];
      int ds0 = dseg[row0 + c];
      int ds1 = dseg[row0 + Wn + c];
      dv0 = min(min(ds0, i0 - bf), min(af - i0, 255));
      dv1 = min(min(ds1, i0 + 1 - bf), min(af - (i0 + 1), 255));
    }
    h2 pk;
    pk.x = (_Float16)(float)dv0;
    pk.y = (_Float16)(float)dv1;
    dvs[e] = pk;
  }
  __syncthreads();

  const h2 A2 = {(_Float16)0.955f, (_Float16)0.955f};
  const h2 BA2 = {(_Float16)0.4143f, (_Float16)0.4143f};
  h2 acc0 = {(_Float16)300.0f, (_Float16)300.0f};
  h2 acc1 = acc0;

#define STEP(k)                                                              \
  {                                                                          \
    const h2 c1 = {(_Float16)(0.955f * (k)), (_Float16)(0.955f * (k))};      \
    const h2 c2 = {(_Float16)(0.4143f * (k)), (_Float16)(0.4143f * (k))};    \
    h2 v = __builtin_elementwise_min(dvs[tx + RAD - (k)],                    \
                                     dvs[tx + RAD + (k)]);                   \
    h2 f = __builtin_elementwise_max(v * BA2 + c1, v * A2 + c2);             \
    if ((k) & 1) acc1 = __builtin_elementwise_min(acc1, f);                  \
    else         acc0 = __builtin_elementwise_min(acc0, f);                  \
  }

#define CHECK(kn)                                                            \
  {                                                                          \
    h2 q = __builtin_elementwise_min(acc0, acc1);                            \
    float mm = fmaxf((float)q.x, (float)q.y);                                \
    for (int s = 1; s < 64; s <<= 1) mm = fmaxf(mm, __shfl_xor(mm, s, 64));  \
    if (0.955f * (float)(kn) >= mm) goto done;                               \
  }

  STEP(0) STEP(1) STEP(2) STEP(3) STEP(4) STEP(5) STEP(6) STEP(7) STEP(8)
  CHECK(9)
  STEP(9) STEP(10) STEP(11) STEP(12)
  CHECK(13)
  STEP(13) STEP(14) STEP(15) STEP(16)
  CHECK(17)
  STEP(17) STEP(18) STEP(19) STEP(20)
  CHECK(21)
  STEP(21) STEP(22) STEP(23) STEP(24)
done:;

  h2 am = __builtin_elementwise_min(acc0, acc1);
  float d0 = (float)am.x, d1 = (float)am.y;
  float w0 = __expf(d0 * (-1.0f / 3.0f)) + 0.1f;
  float w1 = __expf(d1 * (-1.0f / 3.0f)) + 0.1f;

  const int col = c0 + tx;
  const int wi = col >> 5, sh = col & 31;
  unsigned int mw0 = mbits[((size_t)b * Hn + i0) * WPR + wi];
  unsigned int mw1 = mbits[((size_t)b * Hn + i0 + 1) * WPR + wi];
  float t0 = (float)((mw0 >> sh) & 1u);
  float t1 = (float)((mw1 >> sh) & 1u);

  float L0 = x[row0 + col], L1 = x[row0 + Wn + col];
  L0 = fminf(fmaxf(L0, -16.118095f), 16.118095f);
  L1 = fminf(fmaxf(L1, -16.118095f), 16.118095f);
  float bce0 = fmaxf(L0, 0.0f) - L0 * t0 + __logf(1.0f + __expf(-fabsf(L0)));
  float bce1 = fmaxf(L1, 0.0f) - L1 * t1 + __logf(1.0f + __expf(-fabsf(L1)));
  float val = bce0 * w0 + bce1 * w1;

#pragma unroll
  for (int s = 32; s; s >>= 1) val += __shfl_down(val, s, 64);
  if ((tx & 63) == 0) red[tx >> 6] = val;
  __syncthreads();
  if (tx == 0)
    partial[(((b << 8) + by) << 1) + cx] = red[0] + red[1] + red[2] + red[3];
}

// ---------------------------------------------------------------------------
// K4: deterministic final reduction (double accumulation) -> mean.
// ---------------------------------------------------------------------------
__global__ __launch_bounds__(1024) void k_final(
    const float* __restrict__ partial, float* __restrict__ out) {
  __shared__ double red[1024];
  double s = 0.0;
  for (int idx = threadIdx.x; idx < Bn * 512; idx += 1024)
    s += (double)partial[idx];
  red[threadIdx.x] = s;
  __syncthreads();
  for (int st = 512; st; st >>= 1) {
    if (threadIdx.x < st) red[threadIdx.x] += red[threadIdx.x + st];
    __syncthreads();
  }
  if (threadIdx.x == 0)
    out[0] = (float)(red[0] / (double)((size_t)Bn * Hn * Wn));
}

extern "C" void kernel_launch(void* const* d_in, const int* in_sizes, int n_in,
                              void* d_out, int out_size, void* d_ws, size_t ws_size,
                              hipStream_t stream) {
  const float* inputs = (const float*)d_in[0];
  const float* targets = (const float*)d_in[1];
  float* out = (float*)d_out;

  unsigned char* ws = (unsigned char*)d_ws;
  const int nsum = Bn * NSEG * Wn;  // 131072
  unsigned int* mbits = (unsigned int*)ws;                   // 512 KB
  unsigned char* dseg = ws + (512 << 10);                    // 4 MB
  short* Bf = (short*)(ws + (512 << 10) + (4u << 20));       // 256 KB
  short* Bl = Bf + nsum;                                     // 256 KB
  short* before = Bl + nsum;                                 // 256 KB
  short* after = before + nsum;                              // 256 KB
  float* partial = (float*)(after + nsum);                   // 32 KB

  hipLaunchKernelGGL(k_pack, dim3(2048), dim3(256), 0, stream, targets, mbits);
  hipLaunchKernelGGL(k_vdt, dim3(Bn * NSEG * 2), dim3(256), 0, stream, mbits,
                     dseg, Bf, Bl);
  hipLaunchKernelGGL(k_comb, dim3(32), dim3(256), 0, stream, Bf, Bl, before,
                     after);
  {
    dim3 blk(256, 1, 1), grd(2, Hn / 2, Bn);
    hipLaunchKernelGGL(k_loss, grd, blk, 0, stream, inputs, mbits, dseg,
                       before, after, partial);
  }
  hipLaunchKernelGGL(k_final, dim3(1), dim3(1024), 0, stream, partial, out);
}